// Round 1
// baseline (364.474 us; speedup 1.0000x reference)
//
#include <hip/hip_runtime.h>

#define N_ROWS 262144
#define DIM 128

typedef __attribute__((ext_vector_type(8))) short bf16x8;
typedef __attribute__((ext_vector_type(4))) float f32x4;

// ---- ws layout (float offsets) ----
#define WS_S      0        // scalar S = sum(e)
#define WS_SUMEE  8        // 128
#define WS_C      136      // 128  c = W_c2 @ sum_eE
#define WS_B12    264      // 128  b_c1 + b_c2
#define WS_WBF    512      // 32768 bf16 (=16384 floats): Wcat[n][k], n<128: W_c1, else W_c2
#define WS_ZPART  16896    // 2048 per-block exp-sum partials
#define WS_SP     20480    // N    sp_i = E_i . v
#define WS_E      282624   // N    e_i = exp(s_i)
#define WS_WEXP   544768   // N    exp(logit_i)
#define WS_GEPART 806912   // 128*2048 ge partials, layout [d][block]
// total = 1,069,056 floats = 4.28 MB

__device__ __forceinline__ unsigned short f2bf(float f) {
    union { float f; unsigned u; } v; v.f = f;
    unsigned r = v.u + 0x7fffu + ((v.u >> 16) & 1u);
    return (unsigned short)(r >> 16);
}

// ---------------- K1: init accumulators, convert weights to bf16, b12 ----------------
__global__ __launch_bounds__(256) void k1_init(const float* __restrict__ Wc1,
                                               const float* __restrict__ Wc2,
                                               const float* __restrict__ bc1,
                                               const float* __restrict__ bc2,
                                               float* __restrict__ ws) {
    int gid = blockIdx.x * 256 + threadIdx.x;
    unsigned short* wbf = (unsigned short*)(ws + WS_WBF);
    if (gid < 32768) {
        int n = gid >> 7, k = gid & 127;
        float v = (n < 128) ? Wc1[n * 128 + k] : Wc2[(n - 128) * 128 + k];
        wbf[gid] = f2bf(v);
    }
    if (gid < 128) {
        ws[WS_SUMEE + gid] = 0.f;
        ws[WS_B12 + gid] = bc1[gid] + bc2[gid];
    }
    if (gid == 0) ws[WS_S] = 0.f;
}

// ---------------- K2: one pass over E -> sp, e, S, sum_eE ----------------
// 2048 blocks x 256 threads; 128 rows/block; quarter-wave (16 lanes) per row.
__global__ __launch_bounds__(256) void k2_stats(const float* __restrict__ E,
                                                const float* __restrict__ v,
                                                const float* __restrict__ wpa,
                                                const float* __restrict__ bpa,
                                                float* __restrict__ ws) {
    __shared__ float red[16][128];
    __shared__ float redS[16];
    int t = threadIdx.x;
    int wave = t >> 6, lane = t & 63;
    int cl = lane & 15, rs = lane >> 4;
    int row0 = blockIdx.x * 128;
    const float4* E4 = (const float4*)E;

    float4 va = ((const float4*)v)[cl];
    float4 vb = ((const float4*)v)[16 + cl];
    float4 pa = ((const float4*)wpa)[cl];
    float4 pb = ((const float4*)wpa)[16 + cl];
    float bias = bpa[0];

    float4 acc0 = {0.f, 0.f, 0.f, 0.f}, acc1 = {0.f, 0.f, 0.f, 0.f};
    float se = 0.f;
    float* sp_ws = ws + WS_SP;
    float* e_ws = ws + WS_E;

    for (int it = 0; it < 8; ++it) {
        int row = row0 + it * 16 + wave * 4 + rs;
        float4 x0 = E4[row * 32 + cl];
        float4 x1 = E4[row * 32 + 16 + cl];
        float dv = x0.x * va.x + x0.y * va.y + x0.z * va.z + x0.w * va.w
                 + x1.x * vb.x + x1.y * vb.y + x1.z * vb.z + x1.w * vb.w;
        float dp = x0.x * pa.x + x0.y * pa.y + x0.z * pa.z + x0.w * pa.w
                 + x1.x * pb.x + x1.y * pb.y + x1.z * pb.z + x1.w * pb.w;
        for (int off = 1; off < 16; off <<= 1) {
            dv += __shfl_xor(dv, off);
            dp += __shfl_xor(dp, off);
        }
        float e = __expf(dp + bias);
        if (cl == 0) {
            sp_ws[row] = dv;
            e_ws[row] = e;
            se += e;
        }
        acc0.x += e * x0.x; acc0.y += e * x0.y; acc0.z += e * x0.z; acc0.w += e * x0.w;
        acc1.x += e * x1.x; acc1.y += e * x1.y; acc1.z += e * x1.z; acc1.w += e * x1.w;
    }
    int rr = wave * 4 + rs;
    float* dst = red[rr];
    dst[cl * 4 + 0] = acc0.x; dst[cl * 4 + 1] = acc0.y;
    dst[cl * 4 + 2] = acc0.z; dst[cl * 4 + 3] = acc0.w;
    dst[64 + cl * 4 + 0] = acc1.x; dst[64 + cl * 4 + 1] = acc1.y;
    dst[64 + cl * 4 + 2] = acc1.z; dst[64 + cl * 4 + 3] = acc1.w;
    if (cl == 0) redS[rr] = se;
    __syncthreads();
    if (t < 128) {
        float s = 0.f;
        for (int r = 0; r < 16; ++r) s += red[r][t];
        atomicAdd(&ws[WS_SUMEE + t], s);
    }
    if (t == 0) {
        float s = 0.f;
        for (int r = 0; r < 16; ++r) s += redS[r];
        atomicAdd(&ws[WS_S], s);
    }
}

// ---------------- K3: c = W_c2 @ sum_eE (tiny) ----------------
__global__ __launch_bounds__(128) void k3_c(const float* __restrict__ Wc2,
                                            float* __restrict__ ws) {
    int j = threadIdx.x;
    float s = 0.f;
    for (int k = 0; k < 128; ++k) s += Wc2[j * 128 + k] * ws[WS_SUMEE + k];
    ws[WS_C + j] = s;
}

// ---------------- K4: MFMA GEMM + fused epilogue + ge partials ----------------
// 2048 blocks x 512 threads (8 waves); 128 rows/block.
// Wave w computes output col-tiles {w, w+8} (u1[j], u2[j] for j in [w*16, w*16+16))
// for all 8 row-tiles. B-fragments live in registers, loaded once from bf16 Wcat.
__global__ __launch_bounds__(512) void k4_main(const float* __restrict__ E,
                                               const float* __restrict__ wvc,
                                               const float* __restrict__ bvc_p,
                                               float* __restrict__ ws) {
    __shared__ unsigned short Elds[128 * 136];   // bf16, row stride 136 (pad 8)
    __shared__ float c_lds[128], b12_lds[128], wvc_lds[128];
    __shared__ float e_lds[128], dinv_lds[128];
    __shared__ float pim[8][128];
    __shared__ float wexp_lds[128];
    __shared__ float gred[512];

    int t = threadIdx.x;
    int w = t >> 6, lane = t & 63, cl = lane & 15, q = lane >> 4;
    int row0 = blockIdx.x * 128;
    const unsigned short* wbf = (const unsigned short*)(ws + WS_WBF);

    // B fragments (registers): ct = w and w+8
    bf16x8 bfr[2][4];
#pragma unroll
    for (int c2 = 0; c2 < 2; ++c2) {
        int ct = w + c2 * 8;
#pragma unroll
        for (int kt = 0; kt < 4; ++kt)
            bfr[c2][kt] = *(const bf16x8*)(wbf + (ct * 16 + cl) * 128 + kt * 32 + q * 8);
    }

    // Stage E tile -> LDS (fp32 -> bf16)
    const float4* E4 = (const float4*)E + (size_t)row0 * 32;
#pragma unroll
    for (int i = 0; i < 8; ++i) {
        int idx = t + 512 * i;
        int row = idx >> 5, kq = idx & 31;
        float4 x = E4[idx];
        unsigned p0 = (unsigned)f2bf(x.x) | ((unsigned)f2bf(x.y) << 16);
        unsigned p1 = (unsigned)f2bf(x.z) | ((unsigned)f2bf(x.w) << 16);
        uint2* dst = (uint2*)&Elds[row * 136 + kq * 4];
        *dst = make_uint2(p0, p1);
    }
    if (t < 128) {
        c_lds[t] = ws[WS_C + t];
        b12_lds[t] = ws[WS_B12 + t];
        wvc_lds[t] = wvc[t];
        float Sv = ws[WS_S];
        float ev = ws[WS_E + row0 + t];
        e_lds[t] = ev;
        dinv_lds[t] = 1.0f / (Sv - ev);
    }
    __syncthreads();

    // GEMM: U[row][j] over this wave's two col-tiles
    f32x4 acc[8][2];
#pragma unroll
    for (int rt = 0; rt < 8; ++rt)
#pragma unroll
        for (int c2 = 0; c2 < 2; ++c2)
            acc[rt][c2] = (f32x4){0.f, 0.f, 0.f, 0.f};

#pragma unroll
    for (int rt = 0; rt < 8; ++rt) {
        bf16x8 a[4];
#pragma unroll
        for (int kt = 0; kt < 4; ++kt)
            a[kt] = *(const bf16x8*)&Elds[(rt * 16 + cl) * 136 + kt * 32 + q * 8];
#pragma unroll
        for (int kt = 0; kt < 4; ++kt) {
            acc[rt][0] = __builtin_amdgcn_mfma_f32_16x16x32_bf16(a[kt], bfr[0][kt], acc[rt][0], 0, 0, 0);
            acc[rt][1] = __builtin_amdgcn_mfma_f32_16x16x32_bf16(a[kt], bfr[1][kt], acc[rt][1], 0, 0, 0);
        }
    }

    // Epilogue: h = u1 + b12 + (c - e*u2)*dinv; partial pi = wvc * relu(h)
    int j = w * 16 + cl;
    float cj = c_lds[j], b12j = b12_lds[j], wvcj = wvc_lds[j];
#pragma unroll
    for (int rt = 0; rt < 8; ++rt) {
#pragma unroll
        for (int reg = 0; reg < 4; ++reg) {
            int row_it = rt * 16 + q * 4 + reg;
            float er = e_lds[row_it];
            float dinv = dinv_lds[row_it];
            float u1 = acc[rt][0][reg];
            float u2 = acc[rt][1][reg];
            float h = u1 + b12j + (cj - er * u2) * dinv;
            float p = wvcj * fmaxf(h, 0.f);
            p += __shfl_xor(p, 1);
            p += __shfl_xor(p, 2);
            p += __shfl_xor(p, 4);
            p += __shfl_xor(p, 8);
            if (cl == 0) pim[w][row_it] = p;
        }
    }
    __syncthreads();

    // Combine pi across waves, logits -> exp
    float bvc = bvc_p[0];
    if (t < 128) {
        float pi = 0.f;
#pragma unroll
        for (int wv = 0; wv < 8; ++wv) pi += pim[wv][t];
        float logit = ws[WS_SP + row0 + t] + bvc + pi;
        float we = __expf(logit);
        wexp_lds[t] = we;
        ws[WS_WEXP + row0 + t] = we;
    }
    __syncthreads();

    // per-block Z partial (wave 0)
    if (t < 64) {
        float z = wexp_lds[t] + wexp_lds[t + 64];
        for (int off = 1; off < 64; off <<= 1) z += __shfl_xor(z, off);
        if (t == 0) ws[WS_ZPART + blockIdx.x] = z;
    }

    // per-block group-embedding partial: sum_r wexp[r] * E[r][d]  (E re-read, L2-hot)
    int d = t & 127, grp = t >> 7;
    const float* Eb = E + (size_t)row0 * 128;
    float ga = 0.f;
#pragma unroll 4
    for (int r = grp * 32; r < grp * 32 + 32; ++r)
        ga += wexp_lds[r] * Eb[r * 128 + d];
    gred[t] = ga;
    __syncthreads();
    if (t < 128) {
        float tot = gred[t] + gred[t + 128] + gred[t + 256] + gred[t + 384];
        ws[WS_GEPART + t * 2048 + blockIdx.x] = tot;
    }
}

// ---------------- K5: Z reduce (redundant per block) + outputs ----------------
// blocks 0..127: ge[d]; blocks 128..1151: attention weights
__global__ __launch_bounds__(256) void k5_final(const float* __restrict__ ws,
                                                float* __restrict__ out) {
    __shared__ float red[8];
    __shared__ float zsh;
    int t = threadIdx.x, blk = blockIdx.x;

    const float* zp = ws + WS_ZPART;
    float z = 0.f;
#pragma unroll
    for (int k = 0; k < 8; ++k) z += zp[t + 256 * k];
    for (int off = 1; off < 64; off <<= 1) z += __shfl_xor(z, off);
    if ((t & 63) == 0) red[t >> 6] = z;
    __syncthreads();
    if (t == 0) zsh = red[0] + red[1] + red[2] + red[3];
    __syncthreads();
    float invZ = 1.0f / zsh;

    if (blk < 128) {
        const float* gp = ws + WS_GEPART + blk * 2048;
        float s = 0.f;
#pragma unroll
        for (int k = 0; k < 8; ++k) s += gp[t + 256 * k];
        for (int off = 1; off < 64; off <<= 1) s += __shfl_xor(s, off);
        if ((t & 63) == 0) red[4 + (t >> 6)] = s;
        __syncthreads();
        if (t == 0) out[blk] = (red[4] + red[5] + red[6] + red[7]) * invZ;
    } else {
        int i = (blk - 128) * 256 + t;
        out[128 + i] = ws[WS_WEXP + i] * invZ;
    }
}

extern "C" void kernel_launch(void* const* d_in, const int* in_sizes, int n_in,
                              void* d_out, int out_size, void* d_ws, size_t ws_size,
                              hipStream_t stream) {
    const float* E   = (const float*)d_in[0];
    const float* v   = (const float*)d_in[1];
    const float* Wc1 = (const float*)d_in[2];
    const float* bc1 = (const float*)d_in[3];
    const float* Wc2 = (const float*)d_in[4];
    const float* bc2 = (const float*)d_in[5];
    const float* wpa = (const float*)d_in[6];
    const float* bpa = (const float*)d_in[7];
    const float* wvc = (const float*)d_in[8];
    const float* bvc = (const float*)d_in[9];
    float* ws  = (float*)d_ws;
    float* out = (float*)d_out;

    k1_init<<<128, 256, 0, stream>>>(Wc1, Wc2, bc1, bc2, ws);
    k2_stats<<<2048, 256, 0, stream>>>(E, v, wpa, bpa, ws);
    k3_c<<<1, 128, 0, stream>>>(Wc2, ws);
    k4_main<<<2048, 512, 0, stream>>>(E, wvc, bvc, ws);
    k5_final<<<1152, 256, 0, stream>>>(ws, out);
}